// Round 13
// baseline (202.443 us; speedup 1.0000x reference)
//
#include <hip/hip_runtime.h>
#include <math.h>

#define AGENT __HIP_MEMORY_SCOPE_AGENT

// QLSTM: 12-qubit statevector sim, 16 steps x 4 gates x 64 samples.
// 256 WGs x 512 threads: WG = (gate g, sample b), 8 amps/thread.
// Validated math (r7): sigma0 folded into product-state build; sigma1 folded
// into measurement sign masks + head (Qv). Matrices hoisted to named float4
// registers. KEY FIX vs r12: __launch_bounds__(512, 1) -- the previous
// (512, 2) was treated as "min 2 BLOCKS/CU" (CUDA semantics) => 4 waves/SIMD
// => 128-VGPR cap => ~70 regs spilled to scratch (11 MB/dispatch WRITE_SIZE,
// identical across r10-r12). With min 1 block/CU the cap is 256 VGPRs and
// the hoisted working set (~200 regs) fits with zero scratch.

__device__ __forceinline__ float ftanh(float x) {
    x = fminf(fmaxf(x, -15.f), 15.f);
    const float e = __expf(2.f * x);
    return (e - 1.f) / (e + 1.f);
}
__device__ __forceinline__ float fsigm(float x) { return 1.f / (1.f + __expf(-x)); }
__device__ __forceinline__ float gld(const float* p) {
    return __hip_atomic_load(p, __ATOMIC_RELAXED, AGENT);
}

#define CMUL(dr, di, xr, xi, yr, yi) \
    do { dr = (xr)*(yr) - (xi)*(yi); di = (xr)*(yi) + (xi)*(yr); } while (0)

template<int CTRL>
__device__ __forceinline__ float dppf(float x) {   // quad_perm lane swap (VALU)
    return __int_as_float(__builtin_amdgcn_update_dpp(
        0, __float_as_int(x), CTRL, 0xF, 0xF, true));
}

template<int CTRL>
__device__ __forceinline__ void dpprot(float ar[8], float ai[8],
                                       float por, float poi, float ppr, float ppi) {
#pragma unroll
    for (int j = 0; j < 8; ++j) {
        const float qr = dppf<CTRL>(ar[j]);
        const float qi = dppf<CTRL>(ai[j]);
        const float nr = por*ar[j] - poi*ai[j] + ppr*qr - ppi*qi;
        const float ni = por*ai[j] + poi*ar[j] + ppr*qi + ppi*qr;
        ar[j] = nr; ai[j] = ni;
    }
}

__device__ __forceinline__ void shflrot32(float ar[8], float ai[8],
                                          float por, float poi, float ppr, float ppi) {
#pragma unroll
    for (int j = 0; j < 8; ++j) {
        const float qr = __shfl_xor(ar[j], 32);
        const float qi = __shfl_xor(ai[j], 32);
        const float nr = por*ar[j] - poi*ai[j] + ppr*qr - ppi*qi;
        const float ni = por*ai[j] + poi*ar[j] + ppr*qi + ppi*qr;
        ar[j] = nr; ai[j] = ni;
    }
}

// one 2x2 complex gate on amp pair (J0,J1); ma=(m00r,m00i,m01r,m01i),
// mb=(m10r,m10i,m11r,m11i). Compile-time J0/J1 -> SROA-safe.
#define GATE(ma, mb, J0, J1)                                        \
    {   const float a0r = ar[J0], a0i = ai[J0];                     \
        const float a1r = ar[J1], a1i = ai[J1];                     \
        ar[J0] = ma.x*a0r - ma.y*a0i + ma.z*a1r - ma.w*a1i;         \
        ai[J0] = ma.x*a0i + ma.y*a0r + ma.z*a1i + ma.w*a1r;         \
        ar[J1] = mb.x*a0r - mb.y*a0i + mb.z*a1r - mb.w*a1i;         \
        ai[J1] = mb.x*a0i + mb.y*a0r + mb.z*a1i + mb.w*a1r; }

#define ROT_S4(ma, mb) GATE(ma, mb, 0, 4) GATE(ma, mb, 1, 5) \
                       GATE(ma, mb, 2, 6) GATE(ma, mb, 3, 7)
#define ROT_S2(ma, mb) GATE(ma, mb, 0, 2) GATE(ma, mb, 1, 3) \
                       GATE(ma, mb, 4, 6) GATE(ma, mb, 5, 7)
#define ROT_S1(ma, mb) GATE(ma, mb, 0, 1) GATE(ma, mb, 2, 3) \
                       GATE(ma, mb, 4, 5) GATE(ma, mb, 6, 7)

__global__ __launch_bounds__(512, 1)
void qlstm_fused(const float* __restrict__ inputs,
                 const float* __restrict__ wf, const float* __restrict__ wi,
                 const float* __restrict__ wu, const float* __restrict__ wo,
                 const float* __restrict__ fW, const float* __restrict__ fb,
                 const float* __restrict__ iW, const float* __restrict__ ib,
                 const float* __restrict__ uW, const float* __restrict__ ub,
                 const float* __restrict__ oW, const float* __restrict__ ob,
                 float* __restrict__ gact,     // ws: [2][4][64][4]
                 unsigned* __restrict__ ctr,   // ws: [64][16], memset 0
                 float* __restrict__ out)      // 4096 + 256 + 256
{
    // 6144 (not 4096): LDS pad past 80 KB keeps HW occupancy at 1 WG/CU
    // explicit (free: grid is 256 WGs on 256 CUs).
    __shared__ float2 bufA[6144], bufB[6144];
    __shared__ __align__(16) float rotm[192];   // 24 gates x 8 (this WG's type)
    __shared__ __align__(16) float4 wtabx[2][8];// x rows q0..7, double-buffered
    __shared__ __align__(16) float4 wtabh[4];   // h rows q8..11 (per step)
    __shared__ float Wsh[48];
    __shared__ float zred[8][4];

    const int tid = threadIdx.x;
    const int b = blockIdx.x & 63;
    const int g = blockIdx.x >> 6;
    const int l = tid & 63, w = tid >> 6;

    const float* wsel = (g == 0) ? wf : (g == 1) ? wi : (g == 2) ? wu : wo;
    const float* Wsel = (g == 0) ? fW : (g == 1) ? iW : (g == 2) ? uW : oW;
    const float* bsel = (g == 0) ? fb : (g == 1) ? ib : (g == 2) ? ub : ob;

    // ---- one-time staging ----
    if (tid < 24) {                              // Rot matrices (t-invariant)
        const int k = tid;                       // l*12 + qubit
        const float phi = wsel[k*3+0], th = wsel[k*3+1], om = wsel[k*3+2];
        float ct, sth; __sincosf(0.5f * th, &sth, &ct);
        float ca, sa;  __sincosf(0.5f * (phi + om), &sa, &ca);
        float cb, sb2; __sincosf(0.5f * (phi - om), &sb2, &cb);
        float* m = rotm + k * 8;
        m[0] =  ca * ct;  m[1] = -sa * ct;
        m[2] = -cb * sth; m[3] = -sb2 * sth;
        m[4] =  cb * sth; m[5] = -sb2 * sth;
        m[6] =  ca * ct;  m[7] =  sa * ct;
    }
    if (tid < 48) Wsh[tid] = Wsel[tid];
    const float bu = (tid < 4) ? bsel[tid] : 0.f;
    __syncthreads();                             // rotm/Wsh staged

    // x rows for t=0 (needs rotm)
    if (tid >= 64 && tid < 72) {
        const int q = tid - 64;
        float sn, cs; __sincosf(0.5f * inputs[b*8 + q], &sn, &cs);
        const float* m = rotm + q * 8;
        wtabx[0][q] = make_float4(m[0]*cs + m[3]*sn, m[1]*cs - m[2]*sn,
                                  m[4]*cs + m[7]*sn, m[5]*cs - m[6]*sn);
    }

    // ---- hoist rot matrices LDS -> NAMED float4 regs (no arrays) ----
    const float4 T0 = ((const float4*)(rotm + 168))[0];   // q9  m00..m01
    const float4 T1 = ((const float4*)(rotm + 168))[1];   // q9  m10..m11
    const float4 T2 = ((const float4*)(rotm + 176))[0];   // q10
    const float4 T3 = ((const float4*)(rotm + 176))[1];
    const float4 T4 = ((const float4*)(rotm + 184))[0];   // q11
    const float4 T5 = ((const float4*)(rotm + 184))[1];
    const float4 M0 = ((const float4*)(rotm + 128))[0];   // q4
    const float4 M1 = ((const float4*)(rotm + 128))[1];
    const float4 M2 = ((const float4*)(rotm + 136))[0];   // q5
    const float4 M3 = ((const float4*)(rotm + 136))[1];
    const float4 M4 = ((const float4*)(rotm + 144))[0];   // q6
    const float4 M5 = ((const float4*)(rotm + 144))[1];
    const float4 L0 = ((const float4*)(rotm +  96))[0];   // q0
    const float4 L1 = ((const float4*)(rotm +  96))[1];
    const float4 L2 = ((const float4*)(rotm + 104))[0];   // q1
    const float4 L3 = ((const float4*)(rotm + 104))[1];
    const float4 L4 = ((const float4*)(rotm + 112))[0];   // q2
    const float4 L5 = ((const float4*)(rotm + 112))[1];

    const int be8 = l & 1, be7 = (l >> 1) & 1, be3 = (l >> 5) & 1;
    const float4 r8v = *(const float4*)(rotm + 160 + (be8 << 2));   // q8
    const float por8 = be8 ? r8v.z : r8v.x, poi8 = be8 ? r8v.w : r8v.y;
    const float ppr8 = be8 ? r8v.x : r8v.z, ppi8 = be8 ? r8v.y : r8v.w;
    const float4 r7v = *(const float4*)(rotm + 152 + (be7 << 2));   // q7
    const float por7 = be7 ? r7v.z : r7v.x, poi7 = be7 ? r7v.w : r7v.y;
    const float ppr7 = be7 ? r7v.x : r7v.z, ppi7 = be7 ? r7v.y : r7v.w;
    const float4 r3v = *(const float4*)(rotm + 120 + (be3 << 2));   // q3
    const float por3 = be3 ? r3v.z : r3v.x, poi3 = be3 ? r3v.w : r3v.y;
    const float ppr3 = be3 ? r3v.x : r3v.z, ppi3 = be3 ? r3v.y : r3v.w;

    // ---- Q precompute: measurement signs + head matvec folded per slot ----
    const int MSK[12] = {0x555,0xAAA,0x554,0xAA8,0x550,0xAA0,
                         0x540,0xA80,0x500,0xA00,0x155,0x2AA};
    const int qbase = ((l >> 5) << 8) | (w << 5) | (((l >> 3) & 3) << 3) | (l & 7);
    float4 Qv[8];
#pragma unroll
    for (int s = 0; s < 8; ++s) {
        float q0 = 0.f, q1 = 0.f, q2 = 0.f, q3 = 0.f;
        const int idx = qbase | (s << 9);
#pragma unroll
        for (int p = 0; p < 12; ++p) {
            const float sgn = (__popc(idx & MSK[p]) & 1) ? -1.f : 1.f;
            const int m = 11 - p;
            q0 += sgn * Wsh[m];
            q1 += sgn * Wsh[12 + m];
            q2 += sgn * Wsh[24 + m];
            q3 += sgn * Wsh[36 + m];
        }
        Qv[s] = make_float4(q0, q1, q2, q3);
    }

    // ---- t-invariant constants (validated r7 addressing) ----
    const int X0 = (tid << 3) ^ (tid << 2);      // sigma0(tid<<3)
    int bitq[7];                                 // x bits 9..3 -> qubits 2..8
#pragma unroll
    for (int qq = 0; qq < 7; ++qq) bitq[qq] = (X0 >> (9 - qq)) & 1;
    const int b11 = (tid >> 8) & 1;              // qubit 0 row select
    const int b10 = ((tid >> 7) & 1) ^ b11;      // qubit 1 row select
    const int lx  = tid & 1;                     // qubit 9 row select
    const int wbase = (tid << 3) ^ (tid & 15);
    const int rb1 = ((w << 9) | (((l >> 5) & 1) << 8) |
                     (((l >> 3) & 3) << 3) | (l & 7)) ^ ((l >> 3) & 3);
    const int rb2 = ((l << 3) | w) ^ (l & 15);

    float c_ = 0.f, h_ = 0.f;                    // live in lanes 0..3

    __syncthreads();                             // wtabx[0] staged

    for (int t = 0; t < 16; ++t) {
        const int cur = t & 1;
        // ---- prefetch next step's x rows (wave1) ----
        if (t < 15 && tid >= 64 && tid < 72) {
            const int q = tid - 64;
            float sn, cs; __sincosf(0.5f * inputs[(t+1)*512 + b*8 + q], &sn, &cs);
            const float* m = rotm + q * 8;
            wtabx[cur ^ 1][q] = make_float4(m[0]*cs + m[3]*sn, m[1]*cs - m[2]*sn,
                                            m[4]*cs + m[7]*sn, m[5]*cs - m[6]*sn);
        }

        // ---- pre-B0: x-only build sub-tree (overlaps lanes 0..3 spin) ----
        const float* wx = (const float*)&wtabx[cur][0];
        const float2 f2 = *(const float2*)(wx +  8 + bitq[0]*2);
        const float2 f3 = *(const float2*)(wx + 12 + bitq[1]*2);
        const float2 f4 = *(const float2*)(wx + 16 + bitq[2]*2);
        const float2 f5 = *(const float2*)(wx + 20 + bitq[3]*2);
        const float2 f6 = *(const float2*)(wx + 24 + bitq[4]*2);
        const float2 f7 = *(const float2*)(wx + 28 + bitq[5]*2);
        float a23r,a23i, a45r,a45i, a67r,a67i, p47r,p47i, P6r,P6i;
        CMUL(a23r,a23i, f2.x,f2.y, f3.x,f3.y);
        CMUL(a45r,a45i, f4.x,f4.y, f5.x,f5.y);
        CMUL(a67r,a67i, f6.x,f6.y, f7.x,f7.y);
        CMUL(p47r,p47i, a45r,a45i, a67r,a67i);
        CMUL(P6r,P6i,   a23r,a23i, p47r,p47i);
        const float4 R0 = wtabx[cur][0], R1 = wtabx[cur][1];
        const float v0sr = b11 ? R0.z : R0.x, v0si = b11 ? R0.w : R0.y;
        const float v0or = b11 ? R0.x : R0.z, v0oi = b11 ? R0.y : R0.w;
        const float v1sr = b10 ? R1.z : R1.x, v1si = b10 ? R1.w : R1.y;
        const float v1or = b10 ? R1.x : R1.z, v1oi = b10 ? R1.y : R1.w;
        float Er,Ei, Og,Oh, PEr,PEi, POr,POi;
        CMUL(Er,Ei, v0sr,v0si, v1sr,v1si);
        CMUL(Og,Oh, v0or,v0oi, v1or,v1oi);
        CMUL(PEr,PEi, P6r,P6i, Er,Ei);
        CMUL(POr,POi, P6r,P6i, Og,Oh);

        // ---- lanes 0..3: rendezvous spin + recurrence + publish h rows ----
        if (tid < 4) {
            if (t > 0) {
                while (__hip_atomic_load(&ctr[b*16 + (t-1)],
                                         __ATOMIC_RELAXED, AGENT) < 4u)
                    __builtin_amdgcn_s_sleep(2);
                __threadfence();
                const float* ga = gact + ((t-1)&1)*1024 + b*4 + tid;
                const float f_ = gld(ga),       i_ = gld(ga + 256);
                const float u_ = gld(ga + 512), o_ = gld(ga + 768);
                c_ = f_*c_ + i_*u_;
                h_ = o_*ftanh(c_);
                if (g == 0) out[(t-1)*256 + b*4 + tid] = h_;
            }
            float sn, cs; __sincosf(0.5f * h_, &sn, &cs);
            const float* m = rotm + (8 + tid) * 8;
            wtabh[tid] = make_float4(m[0]*cs + m[3]*sn, m[1]*cs - m[2]*sn,
                                     m[4]*cs + m[7]*sn, m[5]*cs - m[6]*sn);
        }
        __syncthreads();   // B0

        // ---- post-B0: h-dependent build completion ----
        const float4 W8 = wtabh[0], R9 = wtabh[1], RA = wtabh[2], RB = wtabh[3];
        const float w8r = bitq[6] ? W8.z : W8.x, w8i = bitq[6] ? W8.w : W8.y;
        float FEr,FEi, FOr,FOi;
        CMUL(FEr,FEi, PEr,PEi, w8r,w8i);
        CMUL(FOr,FOi, POr,POi, w8r,w8i);
        const float w9lr = lx ? R9.z : R9.x, w9li = lx ? R9.w : R9.y;
        const float w9hr = lx ? R9.x : R9.z, w9hi = lx ? R9.y : R9.w;
        float m0r,m0i, m1r,m1i, m2r,m2i, m3r,m3i;
        CMUL(m0r,m0i, w9lr,w9li, RA.x,RA.y);
        CMUL(m1r,m1i, w9lr,w9li, RA.z,RA.w);
        CMUL(m2r,m2i, w9hr,w9hi, RA.x,RA.y);
        CMUL(m3r,m3i, w9hr,w9hi, RA.z,RA.w);
        float ttr[8], tti[8];
        CMUL(ttr[0],tti[0], m0r,m0i, RB.x,RB.y);
        CMUL(ttr[1],tti[1], m0r,m0i, RB.z,RB.w);
        CMUL(ttr[2],tti[2], m1r,m1i, RB.x,RB.y);
        CMUL(ttr[3],tti[3], m1r,m1i, RB.z,RB.w);
        CMUL(ttr[4],tti[4], m2r,m2i, RB.x,RB.y);
        CMUL(ttr[5],tti[5], m2r,m2i, RB.z,RB.w);
        CMUL(ttr[6],tti[6], m3r,m3i, RB.x,RB.y);
        CMUL(ttr[7],tti[7], m3r,m3i, RB.z,RB.w);
        float ar[8], ai[8];                      // slot s: gray(s) selects tt
        CMUL(ar[0],ai[0], FEr,FEi, ttr[0],tti[0]);
        CMUL(ar[1],ai[1], FOr,FOi, ttr[1],tti[1]);
        CMUL(ar[2],ai[2], FEr,FEi, ttr[3],tti[3]);
        CMUL(ar[3],ai[3], FOr,FOi, ttr[2],tti[2]);
        CMUL(ar[4],ai[4], FEr,FEi, ttr[6],tti[6]);
        CMUL(ar[5],ai[5], FOr,FOi, ttr[7],tti[7]);
        CMUL(ar[6],ai[6], FEr,FEi, ttr[5],tti[5]);
        CMUL(ar[7],ai[7], FOr,FOi, ttr[4],tti[4]);

        // ---- Rot L1 gates (named-reg matrices) ----
        ROT_S4(T0, T1)                                // q9
        ROT_S2(T2, T3)                                // q10
        ROT_S1(T4, T5)                                // q11
        dpprot<0xB1>(ar, ai, por8, poi8, ppr8, ppi8); // q8 (xor1)
        dpprot<0x4E>(ar, ai, por7, poi7, ppr7, ppi7); // q7 (xor2)
        shflrot32(ar, ai, por3, poi3, ppr3, ppi3);    // q3 (xor32)

        // ---- exchange1 -> q4,q5,q6 local ----
#pragma unroll
        for (int s = 0; s < 8; ++s)
            bufA[wbase ^ s] = make_float2(ar[s], ai[s]);
        __syncthreads();   // B1
#pragma unroll
        for (int s = 0; s < 8; ++s) {
            const float2 v = bufA[(rb1 | (s << 5)) ^ ((s & 3) << 2)];
            ar[s] = v.x; ai[s] = v.y;
        }
        ROT_S4(M0, M1)                                // q4
        ROT_S2(M2, M3)                                // q5
        ROT_S1(M4, M5)                                // q6
        // ---- exchange2 -> q0,q1,q2 local ----
#pragma unroll
        for (int s = 0; s < 8; ++s)
            bufB[wbase ^ s] = make_float2(ar[s], ai[s]);
        __syncthreads();   // B2
#pragma unroll
        for (int s = 0; s < 8; ++s) {
            const float2 v = bufB[rb2 | (s << 9)];
            ar[s] = v.x; ai[s] = v.y;
        }
        ROT_S4(L0, L1)                                // q0
        ROT_S2(L2, L3)                                // q1
        ROT_S1(L4, L5)                                // q2

        // ---- measure + folded head ----
        float a0 = 0.f, a1 = 0.f, a2 = 0.f, a3 = 0.f;
#pragma unroll
        for (int s = 0; s < 8; ++s) {
            const float p = ar[s]*ar[s] + ai[s]*ai[s];
            a0 += p * Qv[s].x; a1 += p * Qv[s].y;
            a2 += p * Qv[s].z; a3 += p * Qv[s].w;
        }
        // butterfly component-split reduction: lane ends holding comp (l&3)
        {
            const float s1 = (l & 1) ? a0 : a1;
            const float k1 = (l & 1) ? a1 : a0;
            const float r01 = k1 + __shfl_xor(s1, 1);
            const float s2 = (l & 1) ? a2 : a3;
            const float k2 = (l & 1) ? a3 : a2;
            const float r23 = k2 + __shfl_xor(s2, 1);
            const float s3 = (l & 2) ? r01 : r23;
            const float k3 = (l & 2) ? r23 : r01;
            float rc = k3 + __shfl_xor(s3, 2);
            rc += __shfl_xor(rc, 4);
            rc += __shfl_xor(rc, 8);
            rc += __shfl_xor(rc, 16);
            rc += __shfl_xor(rc, 32);
            if (l < 4) zred[w][l] = rc;
        }
        __syncthreads();   // B3

        if (tid < 4) {
            float tot = bu;
#pragma unroll
            for (int wv = 0; wv < 8; ++wv) tot += zred[wv][tid];
            const float act = (g == 2) ? ftanh(tot) : fsigm(tot);
            __hip_atomic_store(&gact[(t&1)*1024 + g*256 + b*4 + tid], act,
                               __ATOMIC_RELAXED, AGENT);
        }
        if (tid == 0)
            __hip_atomic_fetch_add(&ctr[b*16 + t], 1u, __ATOMIC_RELEASE, AGENT);
    }

    // ==== finalize: consume step-15 activations (g==0, lanes 0..3) ====
    if (g == 0 && tid < 4) {
        while (__hip_atomic_load(&ctr[b*16 + 15], __ATOMIC_RELAXED, AGENT) < 4u)
            __builtin_amdgcn_s_sleep(2);
        __threadfence();
        const float* ga = gact + 1024 + b*4 + tid;       // slot 15&1 = 1
        const float f_ = gld(ga),       i_ = gld(ga + 256);
        const float u_ = gld(ga + 512), o_ = gld(ga + 768);
        const float cn = f_*c_ + i_*u_;
        const float hn = o_*ftanh(cn);
        out[3840 + b*4 + tid] = hn;   // outputs[15]
        out[4096 + b*4 + tid] = hn;   // hx
        out[4352 + b*4 + tid] = cn;   // cx
    }
}

extern "C" void kernel_launch(void* const* d_in, const int* in_sizes, int n_in,
                              void* d_out, int out_size, void* d_ws, size_t ws_size,
                              hipStream_t stream) {
    (void)in_sizes; (void)n_in; (void)out_size; (void)ws_size;
    const float* inputs = (const float*)d_in[0];
    const float* wf = (const float*)d_in[1];
    const float* wi = (const float*)d_in[2];
    const float* wu = (const float*)d_in[3];
    const float* wo = (const float*)d_in[4];
    const float* fW = (const float*)d_in[5];
    const float* fb = (const float*)d_in[6];
    const float* iW = (const float*)d_in[7];
    const float* ib = (const float*)d_in[8];
    const float* uW = (const float*)d_in[9];
    const float* ub = (const float*)d_in[10];
    const float* oW = (const float*)d_in[11];
    const float* ob = (const float*)d_in[12];
    float* out = (float*)d_out;
    unsigned* ctr = (unsigned*)d_ws;               // [64][16]
    float* gact = (float*)d_ws + 1024;             // [2][4][64][4]

    hipMemsetAsync(ctr, 0, 1024 * sizeof(unsigned), stream);

    void* args[] = { (void*)&inputs, (void*)&wf, (void*)&wi, (void*)&wu, (void*)&wo,
                     (void*)&fW, (void*)&fb, (void*)&iW, (void*)&ib,
                     (void*)&uW, (void*)&ub, (void*)&oW, (void*)&ob,
                     (void*)&gact, (void*)&ctr, (void*)&out };
    hipError_t err = hipLaunchCooperativeKernel((const void*)qlstm_fused,
                                                dim3(256), dim3(512),
                                                args, 0, stream);
    if (err != hipSuccess) {
        // Fallback: plain launch; 256 WGs (1/CU) co-resident on idle device.
        qlstm_fused<<<dim3(256), dim3(512), 0, stream>>>(
            inputs, wf, wi, wu, wo, fW, fb, iW, ib, uW, ub, oW, ob,
            gact, ctr, out);
    }
}

// Round 14
// 167.575 us; speedup vs baseline: 1.2081x; 1.2081x over previous
//
#include <hip/hip_runtime.h>
#include <math.h>

#define AGENT __HIP_MEMORY_SCOPE_AGENT

// QLSTM: 12-qubit statevector sim, 16 steps x 4 gates x 64 samples.
// 256 WGs x 512 threads: WG = (gate g, sample b), 8 amps/thread.
// Validated math (r7): sigma0 folded into product-state build; sigma1 folded
// into measurement sign masks + head (Qv).
// r14 FIX: r10-r13 spilled (VGPR capped at 128, ~21 floats to scratch,
// 11 MB/dispatch) because ~72 persistent floats of hoisted Rot matrices
// exceed the allocator's budget. Matrices go BACK to use-site LDS float4
// reads (r7-proven: VGPR=100, zero spill; wave-uniform ds_read_b128 =
// broadcast, conflict-free). Structural wins kept: x-row double-buffered
// prefetch, pre-B0 x-subtree overlapping the rendezvous spin, butterfly
// component-split reduction. Allocator range set via amdgpu_waves_per_eu(1,2).

__device__ __forceinline__ float ftanh(float x) {
    x = fminf(fmaxf(x, -15.f), 15.f);
    const float e = __expf(2.f * x);
    return (e - 1.f) / (e + 1.f);
}
__device__ __forceinline__ float fsigm(float x) { return 1.f / (1.f + __expf(-x)); }
__device__ __forceinline__ float gld(const float* p) {
    return __hip_atomic_load(p, __ATOMIC_RELAXED, AGENT);
}

#define CMUL(dr, di, xr, xi, yr, yi) \
    do { dr = (xr)*(yr) - (xi)*(yi); di = (xr)*(yi) + (xi)*(yr); } while (0)

template<int CTRL>
__device__ __forceinline__ float dppf(float x) {   // quad_perm lane swap (VALU)
    return __int_as_float(__builtin_amdgcn_update_dpp(
        0, __float_as_int(x), CTRL, 0xF, 0xF, true));
}

template<int CTRL>
__device__ __forceinline__ void dpprot(float ar[8], float ai[8],
                                       float por, float poi, float ppr, float ppi) {
#pragma unroll
    for (int j = 0; j < 8; ++j) {
        const float qr = dppf<CTRL>(ar[j]);
        const float qi = dppf<CTRL>(ai[j]);
        const float nr = por*ar[j] - poi*ai[j] + ppr*qr - ppi*qi;
        const float ni = por*ai[j] + poi*ar[j] + ppr*qi + ppi*qr;
        ar[j] = nr; ai[j] = ni;
    }
}

__device__ __forceinline__ void shflrot32(float ar[8], float ai[8],
                                          float por, float poi, float ppr, float ppi) {
#pragma unroll
    for (int j = 0; j < 8; ++j) {
        const float qr = __shfl_xor(ar[j], 32);
        const float qi = __shfl_xor(ai[j], 32);
        const float nr = por*ar[j] - poi*ai[j] + ppr*qr - ppi*qi;
        const float ni = por*ai[j] + poi*ar[j] + ppr*qi + ppi*qr;
        ar[j] = nr; ai[j] = ni;
    }
}

// one 2x2 complex gate on amp pair (J0,J1); ma=(m00r,m00i,m01r,m01i),
// mb=(m10r,m10i,m11r,m11i). Compile-time J0/J1 -> SROA-safe.
#define GATE(ma, mb, J0, J1)                                        \
    {   const float a0r = ar[J0], a0i = ai[J0];                     \
        const float a1r = ar[J1], a1i = ai[J1];                     \
        ar[J0] = ma.x*a0r - ma.y*a0i + ma.z*a1r - ma.w*a1i;         \
        ai[J0] = ma.x*a0i + ma.y*a0r + ma.z*a1i + ma.w*a1r;         \
        ar[J1] = mb.x*a0r - mb.y*a0i + mb.z*a1r - mb.w*a1i;         \
        ai[J1] = mb.x*a0i + mb.y*a0r + mb.z*a1i + mb.w*a1r; }

#define ROT_S4(ma, mb) GATE(ma, mb, 0, 4) GATE(ma, mb, 1, 5) \
                       GATE(ma, mb, 2, 6) GATE(ma, mb, 3, 7)
#define ROT_S2(ma, mb) GATE(ma, mb, 0, 2) GATE(ma, mb, 1, 3) \
                       GATE(ma, mb, 4, 6) GATE(ma, mb, 5, 7)
#define ROT_S1(ma, mb) GATE(ma, mb, 0, 1) GATE(ma, mb, 2, 3) \
                       GATE(ma, mb, 4, 5) GATE(ma, mb, 6, 7)

// rot3 on slot qubits with matrices loaded AT USE SITE from LDS (broadcast).
#define ROT3_LDS(off)                                               \
    {   const float4 maA = ((const float4*)(rotm + (off)))[0];      \
        const float4 mbA = ((const float4*)(rotm + (off)))[1];      \
        ROT_S4(maA, mbA) }                                          \
    {   const float4 maB = ((const float4*)(rotm + (off) + 8))[0];  \
        const float4 mbB = ((const float4*)(rotm + (off) + 8))[1];  \
        ROT_S2(maB, mbB) }                                          \
    {   const float4 maC = ((const float4*)(rotm + (off) + 16))[0]; \
        const float4 mbC = ((const float4*)(rotm + (off) + 16))[1]; \
        ROT_S1(maC, mbC) }

__global__ __attribute__((amdgpu_flat_work_group_size(512, 512)))
__attribute__((amdgpu_waves_per_eu(1, 2)))
void qlstm_fused(const float* __restrict__ inputs,
                 const float* __restrict__ wf, const float* __restrict__ wi,
                 const float* __restrict__ wu, const float* __restrict__ wo,
                 const float* __restrict__ fW, const float* __restrict__ fb,
                 const float* __restrict__ iW, const float* __restrict__ ib,
                 const float* __restrict__ uW, const float* __restrict__ ub,
                 const float* __restrict__ oW, const float* __restrict__ ob,
                 float* __restrict__ gact,     // ws: [2][4][64][4]
                 unsigned* __restrict__ ctr,   // ws: [64][16], memset 0
                 float* __restrict__ out)      // 4096 + 256 + 256
{
    __shared__ float2 bufA[6144], bufB[6144];
    __shared__ __align__(16) float rotm[192];   // 24 gates x 8 (this WG's type)
    __shared__ __align__(16) float4 wtabx[2][8];// x rows q0..7, double-buffered
    __shared__ __align__(16) float4 wtabh[4];   // h rows q8..11 (per step)
    __shared__ float Wsh[48];
    __shared__ float zred[8][4];

    const int tid = threadIdx.x;
    const int b = blockIdx.x & 63;
    const int g = blockIdx.x >> 6;
    const int l = tid & 63, w = tid >> 6;

    const float* wsel = (g == 0) ? wf : (g == 1) ? wi : (g == 2) ? wu : wo;
    const float* Wsel = (g == 0) ? fW : (g == 1) ? iW : (g == 2) ? uW : oW;
    const float* bsel = (g == 0) ? fb : (g == 1) ? ib : (g == 2) ? ub : ob;

    // ---- one-time staging ----
    if (tid < 24) {                              // Rot matrices (t-invariant)
        const int k = tid;                       // l*12 + qubit
        const float phi = wsel[k*3+0], th = wsel[k*3+1], om = wsel[k*3+2];
        float ct, sth; __sincosf(0.5f * th, &sth, &ct);
        float ca, sa;  __sincosf(0.5f * (phi + om), &sa, &ca);
        float cb, sb2; __sincosf(0.5f * (phi - om), &sb2, &cb);
        float* m = rotm + k * 8;
        m[0] =  ca * ct;  m[1] = -sa * ct;
        m[2] = -cb * sth; m[3] = -sb2 * sth;
        m[4] =  cb * sth; m[5] = -sb2 * sth;
        m[6] =  ca * ct;  m[7] =  sa * ct;
    }
    if (tid < 48) Wsh[tid] = Wsel[tid];
    const float bu = (tid < 4) ? bsel[tid] : 0.f;
    __syncthreads();                             // rotm/Wsh staged

    // x rows for t=0 (needs rotm)
    if (tid >= 64 && tid < 72) {
        const int q = tid - 64;
        float sn, cs; __sincosf(0.5f * inputs[b*8 + q], &sn, &cs);
        const float* m = rotm + q * 8;
        wtabx[0][q] = make_float4(m[0]*cs + m[3]*sn, m[1]*cs - m[2]*sn,
                                  m[4]*cs + m[7]*sn, m[5]*cs - m[6]*sn);
    }

    // ---- hoist only the small per-lane DPP gate rows (12 floats) ----
    const int be8 = l & 1, be7 = (l >> 1) & 1, be3 = (l >> 5) & 1;
    const float4 r8v = *(const float4*)(rotm + 160 + (be8 << 2));   // q8
    const float por8 = be8 ? r8v.z : r8v.x, poi8 = be8 ? r8v.w : r8v.y;
    const float ppr8 = be8 ? r8v.x : r8v.z, ppi8 = be8 ? r8v.y : r8v.w;
    const float4 r7v = *(const float4*)(rotm + 152 + (be7 << 2));   // q7
    const float por7 = be7 ? r7v.z : r7v.x, poi7 = be7 ? r7v.w : r7v.y;
    const float ppr7 = be7 ? r7v.x : r7v.z, ppi7 = be7 ? r7v.y : r7v.w;
    const float4 r3v = *(const float4*)(rotm + 120 + (be3 << 2));   // q3
    const float por3 = be3 ? r3v.z : r3v.x, poi3 = be3 ? r3v.w : r3v.y;
    const float ppr3 = be3 ? r3v.x : r3v.z, ppi3 = be3 ? r3v.y : r3v.w;

    // ---- Q precompute: measurement signs + head matvec folded per slot ----
    const int MSK[12] = {0x555,0xAAA,0x554,0xAA8,0x550,0xAA0,
                         0x540,0xA80,0x500,0xA00,0x155,0x2AA};
    const int qbase = ((l >> 5) << 8) | (w << 5) | (((l >> 3) & 3) << 3) | (l & 7);
    float4 Qv[8];
#pragma unroll
    for (int s = 0; s < 8; ++s) {
        float q0 = 0.f, q1 = 0.f, q2 = 0.f, q3 = 0.f;
        const int idx = qbase | (s << 9);
#pragma unroll
        for (int p = 0; p < 12; ++p) {
            const float sgn = (__popc(idx & MSK[p]) & 1) ? -1.f : 1.f;
            const int m = 11 - p;
            q0 += sgn * Wsh[m];
            q1 += sgn * Wsh[12 + m];
            q2 += sgn * Wsh[24 + m];
            q3 += sgn * Wsh[36 + m];
        }
        Qv[s] = make_float4(q0, q1, q2, q3);
    }

    // ---- t-invariant constants (validated r7 addressing) ----
    const int X0 = (tid << 3) ^ (tid << 2);      // sigma0(tid<<3)
    int bitq[7];                                 // x bits 9..3 -> qubits 2..8
#pragma unroll
    for (int qq = 0; qq < 7; ++qq) bitq[qq] = (X0 >> (9 - qq)) & 1;
    const int b11 = (tid >> 8) & 1;              // qubit 0 row select
    const int b10 = ((tid >> 7) & 1) ^ b11;      // qubit 1 row select
    const int lx  = tid & 1;                     // qubit 9 row select
    const int wbase = (tid << 3) ^ (tid & 15);
    const int rb1 = ((w << 9) | (((l >> 5) & 1) << 8) |
                     (((l >> 3) & 3) << 3) | (l & 7)) ^ ((l >> 3) & 3);
    const int rb2 = ((l << 3) | w) ^ (l & 15);

    float c_ = 0.f, h_ = 0.f;                    // live in lanes 0..3

    __syncthreads();                             // wtabx[0] staged

    for (int t = 0; t < 16; ++t) {
        const int cur = t & 1;
        // ---- prefetch next step's x rows (wave1) ----
        if (t < 15 && tid >= 64 && tid < 72) {
            const int q = tid - 64;
            float sn, cs; __sincosf(0.5f * inputs[(t+1)*512 + b*8 + q], &sn, &cs);
            const float* m = rotm + q * 8;
            wtabx[cur ^ 1][q] = make_float4(m[0]*cs + m[3]*sn, m[1]*cs - m[2]*sn,
                                            m[4]*cs + m[7]*sn, m[5]*cs - m[6]*sn);
        }

        // ---- pre-B0: x-only build sub-tree (overlaps lanes 0..3 spin) ----
        const float* wx = (const float*)&wtabx[cur][0];
        const float2 f2 = *(const float2*)(wx +  8 + bitq[0]*2);
        const float2 f3 = *(const float2*)(wx + 12 + bitq[1]*2);
        const float2 f4 = *(const float2*)(wx + 16 + bitq[2]*2);
        const float2 f5 = *(const float2*)(wx + 20 + bitq[3]*2);
        const float2 f6 = *(const float2*)(wx + 24 + bitq[4]*2);
        const float2 f7 = *(const float2*)(wx + 28 + bitq[5]*2);
        float a23r,a23i, a45r,a45i, a67r,a67i, p47r,p47i, P6r,P6i;
        CMUL(a23r,a23i, f2.x,f2.y, f3.x,f3.y);
        CMUL(a45r,a45i, f4.x,f4.y, f5.x,f5.y);
        CMUL(a67r,a67i, f6.x,f6.y, f7.x,f7.y);
        CMUL(p47r,p47i, a45r,a45i, a67r,a67i);
        CMUL(P6r,P6i,   a23r,a23i, p47r,p47i);
        const float4 R0 = wtabx[cur][0], R1 = wtabx[cur][1];
        const float v0sr = b11 ? R0.z : R0.x, v0si = b11 ? R0.w : R0.y;
        const float v0or = b11 ? R0.x : R0.z, v0oi = b11 ? R0.y : R0.w;
        const float v1sr = b10 ? R1.z : R1.x, v1si = b10 ? R1.w : R1.y;
        const float v1or = b10 ? R1.x : R1.z, v1oi = b10 ? R1.y : R1.w;
        float Er,Ei, Og,Oh, PEr,PEi, POr,POi;
        CMUL(Er,Ei, v0sr,v0si, v1sr,v1si);
        CMUL(Og,Oh, v0or,v0oi, v1or,v1oi);
        CMUL(PEr,PEi, P6r,P6i, Er,Ei);
        CMUL(POr,POi, P6r,P6i, Og,Oh);

        // ---- lanes 0..3: rendezvous spin + recurrence + publish h rows ----
        if (tid < 4) {
            if (t > 0) {
                while (__hip_atomic_load(&ctr[b*16 + (t-1)],
                                         __ATOMIC_RELAXED, AGENT) < 4u)
                    __builtin_amdgcn_s_sleep(2);
                __threadfence();
                const float* ga = gact + ((t-1)&1)*1024 + b*4 + tid;
                const float f_ = gld(ga),       i_ = gld(ga + 256);
                const float u_ = gld(ga + 512), o_ = gld(ga + 768);
                c_ = f_*c_ + i_*u_;
                h_ = o_*ftanh(c_);
                if (g == 0) out[(t-1)*256 + b*4 + tid] = h_;
            }
            float sn, cs; __sincosf(0.5f * h_, &sn, &cs);
            const float* m = rotm + (8 + tid) * 8;
            wtabh[tid] = make_float4(m[0]*cs + m[3]*sn, m[1]*cs - m[2]*sn,
                                     m[4]*cs + m[7]*sn, m[5]*cs - m[6]*sn);
        }
        __syncthreads();   // B0

        // ---- post-B0: h-dependent build completion ----
        const float4 W8 = wtabh[0], R9 = wtabh[1], RA = wtabh[2], RB = wtabh[3];
        const float w8r = bitq[6] ? W8.z : W8.x, w8i = bitq[6] ? W8.w : W8.y;
        float FEr,FEi, FOr,FOi;
        CMUL(FEr,FEi, PEr,PEi, w8r,w8i);
        CMUL(FOr,FOi, POr,POi, w8r,w8i);
        const float w9lr = lx ? R9.z : R9.x, w9li = lx ? R9.w : R9.y;
        const float w9hr = lx ? R9.x : R9.z, w9hi = lx ? R9.y : R9.w;
        float m0r,m0i, m1r,m1i, m2r,m2i, m3r,m3i;
        CMUL(m0r,m0i, w9lr,w9li, RA.x,RA.y);
        CMUL(m1r,m1i, w9lr,w9li, RA.z,RA.w);
        CMUL(m2r,m2i, w9hr,w9hi, RA.x,RA.y);
        CMUL(m3r,m3i, w9hr,w9hi, RA.z,RA.w);
        float ttr[8], tti[8];
        CMUL(ttr[0],tti[0], m0r,m0i, RB.x,RB.y);
        CMUL(ttr[1],tti[1], m0r,m0i, RB.z,RB.w);
        CMUL(ttr[2],tti[2], m1r,m1i, RB.x,RB.y);
        CMUL(ttr[3],tti[3], m1r,m1i, RB.z,RB.w);
        CMUL(ttr[4],tti[4], m2r,m2i, RB.x,RB.y);
        CMUL(ttr[5],tti[5], m2r,m2i, RB.z,RB.w);
        CMUL(ttr[6],tti[6], m3r,m3i, RB.x,RB.y);
        CMUL(ttr[7],tti[7], m3r,m3i, RB.z,RB.w);
        float ar[8], ai[8];                      // slot s: gray(s) selects tt
        CMUL(ar[0],ai[0], FEr,FEi, ttr[0],tti[0]);
        CMUL(ar[1],ai[1], FOr,FOi, ttr[1],tti[1]);
        CMUL(ar[2],ai[2], FEr,FEi, ttr[3],tti[3]);
        CMUL(ar[3],ai[3], FOr,FOi, ttr[2],tti[2]);
        CMUL(ar[4],ai[4], FEr,FEi, ttr[6],tti[6]);
        CMUL(ar[5],ai[5], FOr,FOi, ttr[7],tti[7]);
        CMUL(ar[6],ai[6], FEr,FEi, ttr[5],tti[5]);
        CMUL(ar[7],ai[7], FOr,FOi, ttr[4],tti[4]);

        // ---- Rot L1 gates (matrices from LDS at use site, broadcast) ----
        ROT3_LDS(168)                                 // q9,q10,q11
        dpprot<0xB1>(ar, ai, por8, poi8, ppr8, ppi8); // q8 (xor1)
        dpprot<0x4E>(ar, ai, por7, poi7, ppr7, ppi7); // q7 (xor2)
        shflrot32(ar, ai, por3, poi3, ppr3, ppi3);    // q3 (xor32)

        // ---- exchange1 -> q4,q5,q6 local ----
#pragma unroll
        for (int s = 0; s < 8; ++s)
            bufA[wbase ^ s] = make_float2(ar[s], ai[s]);
        __syncthreads();   // B1
#pragma unroll
        for (int s = 0; s < 8; ++s) {
            const float2 v = bufA[(rb1 | (s << 5)) ^ ((s & 3) << 2)];
            ar[s] = v.x; ai[s] = v.y;
        }
        ROT3_LDS(128)                                 // q4,q5,q6
        // ---- exchange2 -> q0,q1,q2 local ----
#pragma unroll
        for (int s = 0; s < 8; ++s)
            bufB[wbase ^ s] = make_float2(ar[s], ai[s]);
        __syncthreads();   // B2
#pragma unroll
        for (int s = 0; s < 8; ++s) {
            const float2 v = bufB[rb2 | (s << 9)];
            ar[s] = v.x; ai[s] = v.y;
        }
        ROT3_LDS(96)                                  // q0,q1,q2

        // ---- measure + folded head ----
        float a0 = 0.f, a1 = 0.f, a2 = 0.f, a3 = 0.f;
#pragma unroll
        for (int s = 0; s < 8; ++s) {
            const float p = ar[s]*ar[s] + ai[s]*ai[s];
            a0 += p * Qv[s].x; a1 += p * Qv[s].y;
            a2 += p * Qv[s].z; a3 += p * Qv[s].w;
        }
        // butterfly component-split reduction: lane ends holding comp (l&3)
        {
            const float s1 = (l & 1) ? a0 : a1;
            const float k1 = (l & 1) ? a1 : a0;
            const float r01 = k1 + __shfl_xor(s1, 1);
            const float s2 = (l & 1) ? a2 : a3;
            const float k2 = (l & 1) ? a3 : a2;
            const float r23 = k2 + __shfl_xor(s2, 1);
            const float s3 = (l & 2) ? r01 : r23;
            const float k3 = (l & 2) ? r23 : r01;
            float rc = k3 + __shfl_xor(s3, 2);
            rc += __shfl_xor(rc, 4);
            rc += __shfl_xor(rc, 8);
            rc += __shfl_xor(rc, 16);
            rc += __shfl_xor(rc, 32);
            if (l < 4) zred[w][l] = rc;
        }
        __syncthreads();   // B3

        if (tid < 4) {
            float tot = bu;
#pragma unroll
            for (int wv = 0; wv < 8; ++wv) tot += zred[wv][tid];
            const float act = (g == 2) ? ftanh(tot) : fsigm(tot);
            __hip_atomic_store(&gact[(t&1)*1024 + g*256 + b*4 + tid], act,
                               __ATOMIC_RELAXED, AGENT);
        }
        if (tid == 0)
            __hip_atomic_fetch_add(&ctr[b*16 + t], 1u, __ATOMIC_RELEASE, AGENT);
    }

    // ==== finalize: consume step-15 activations (g==0, lanes 0..3) ====
    if (g == 0 && tid < 4) {
        while (__hip_atomic_load(&ctr[b*16 + 15], __ATOMIC_RELAXED, AGENT) < 4u)
            __builtin_amdgcn_s_sleep(2);
        __threadfence();
        const float* ga = gact + 1024 + b*4 + tid;       // slot 15&1 = 1
        const float f_ = gld(ga),       i_ = gld(ga + 256);
        const float u_ = gld(ga + 512), o_ = gld(ga + 768);
        const float cn = f_*c_ + i_*u_;
        const float hn = o_*ftanh(cn);
        out[3840 + b*4 + tid] = hn;   // outputs[15]
        out[4096 + b*4 + tid] = hn;   // hx
        out[4352 + b*4 + tid] = cn;   // cx
    }
}

extern "C" void kernel_launch(void* const* d_in, const int* in_sizes, int n_in,
                              void* d_out, int out_size, void* d_ws, size_t ws_size,
                              hipStream_t stream) {
    (void)in_sizes; (void)n_in; (void)out_size; (void)ws_size;
    const float* inputs = (const float*)d_in[0];
    const float* wf = (const float*)d_in[1];
    const float* wi = (const float*)d_in[2];
    const float* wu = (const float*)d_in[3];
    const float* wo = (const float*)d_in[4];
    const float* fW = (const float*)d_in[5];
    const float* fb = (const float*)d_in[6];
    const float* iW = (const float*)d_in[7];
    const float* ib = (const float*)d_in[8];
    const float* uW = (const float*)d_in[9];
    const float* ub = (const float*)d_in[10];
    const float* oW = (const float*)d_in[11];
    const float* ob = (const float*)d_in[12];
    float* out = (float*)d_out;
    unsigned* ctr = (unsigned*)d_ws;               // [64][16]
    float* gact = (float*)d_ws + 1024;             // [2][4][64][4]

    hipMemsetAsync(ctr, 0, 1024 * sizeof(unsigned), stream);

    void* args[] = { (void*)&inputs, (void*)&wf, (void*)&wi, (void*)&wu, (void*)&wo,
                     (void*)&fW, (void*)&fb, (void*)&iW, (void*)&ib,
                     (void*)&uW, (void*)&ub, (void*)&oW, (void*)&ob,
                     (void*)&gact, (void*)&ctr, (void*)&out };
    hipError_t err = hipLaunchCooperativeKernel((const void*)qlstm_fused,
                                                dim3(256), dim3(512),
                                                args, 0, stream);
    if (err != hipSuccess) {
        // Fallback: plain launch; 256 WGs (1/CU) co-resident on idle device.
        qlstm_fused<<<dim3(256), dim3(512), 0, stream>>>(
            inputs, wf, wi, wu, wo, fW, fb, iW, ib, uW, ub, oW, ob,
            gact, ctr, out);
    }
}